// Round 13
// baseline (125.831 us; speedup 1.0000x reference)
//
#include <hip/hip_runtime.h>

#define NROWS 8192
#define DIMX  128              // raw feature dims
#define KB    192              // i8 K: 128 data + 40 one-hot (4/class) + 24 zero pad
#define KSEG  12               // 16B segments per row
#define PTB   24576            // bytes per 128-row panel tile (128*192)
#define NKS   3                // MFMA K-steps of 64
#define NCLS  10
#define GAPV  0.4f
#define DEBIAS 504.03125f      // 2*4*127*127/256 — exact fp32
#define SCL   (-0.0078125f)    // -2/256
#define RGR   256              // rows per block (4 waves x 64 rows)
#define NRG   (NROWS / RGR)        // 32 rowgroups
#define CHUNK 512              // cols per block
#define NCHUNK (NROWS / CHUNK)     // 16 col-chunks
#define SLAB  64               // cols per LDS slab
#define NSLAB (CHUNK / SLAB)       // 8 slabs

typedef __attribute__((ext_vector_type(4))) int i32x4;

// async 16B/lane global->LDS DMA
#define GLOAD_LDS16(g, l)                                              \
  __builtin_amdgcn_global_load_lds(                                    \
      (const __attribute__((address_space(1))) void*)(g),              \
      (__attribute__((address_space(3))) void*)(l), 16, 0, 0)

__device__ __forceinline__ int q8(float v) {  // round-to-nearest int8 of 16*x
  int q = (int)rintf(16.f * v);
  return q > 127 ? 127 : (q < -127 ? -127 : q);
}

// ---- kernel 1: build i8 PANEL arrays (K=192), sq, confusion, zero ctrs ----
// panel byte addr = (row>>7)*PTB + kseg*2048 + (row&127)*16 + (byte&15)
// row content: [q8(16x)[0..127], A:+127/B:-127 on dims 128+4c..131+4c for c=cls, 0 pad]
// => D = q_a . q_b = 256*dot_approx - 64516*[same]
//    cand = sq_j + SCL*D = sq_j - 2dot + 504.03125*[same]
__global__ __launch_bounds__(256) void prep_k(const float* __restrict__ x,
                                              const int* __restrict__ tgt,
                                              const float* __restrict__ pred,
                                              char* __restrict__ xa,
                                              char* __restrict__ xbm,
                                              float* __restrict__ sq,
                                              int* __restrict__ conf,
                                              unsigned* __restrict__ ctrs) {
  if (blockIdx.x == 0 && threadIdx.x < 3) ctrs[threadIdx.x] = 0u;  // g_done, Ssum, Csum

  const int wave = threadIdx.x >> 6;
  const int lane = threadIdx.x & 63;
  const int row  = blockIdx.x * 4 + wave;
  const float2 f2 = ((const float2*)(x + (size_t)row * DIMX))[lane];
  float s = f2.x * f2.x + f2.y * f2.y;
  #pragma unroll
  for (int m = 1; m < 64; m <<= 1) s += __shfl_xor(s, m, 64);

  char* basea = xa  + (size_t)(row >> 7) * PTB + (size_t)(row & 127) * 16;
  char* baseb = xbm + (size_t)(row >> 7) * PTB + (size_t)(row & 127) * 16;
  {  // data elems e=2L,2L+1 -> kseg = L>>3, byte (L&7)*2
    const int q0 = q8(f2.x), q1 = q8(f2.y);
    const unsigned short u = (unsigned short)((q0 & 0xFF) | ((q1 & 0xFF) << 8));
    const size_t off = (size_t)(lane >> 3) * 2048 + (lane & 7) * 2;
    *(unsigned short*)(basea + off) = u;
    *(unsigned short*)(baseb + off) = u;
  }
  const int cls = tgt[row];
  if (lane < 32) {  // aug elems e = 128 + j, j = 2*lane, 2*lane+1
    const int j = 2 * lane;
    const int c = j >> 2;                  // class block (4 dims each)
    const bool hit = (c < NCLS) && (c == cls);
    const unsigned short ua = hit ? (unsigned short)0x7F7F : 0;  // +127,+127
    const unsigned short ub = hit ? (unsigned short)0x8181 : 0;  // -127,-127
    const size_t off = (size_t)(8 + (j >> 4)) * 2048 + (j & 15);
    *(unsigned short*)(basea + off) = ua;
    *(unsigned short*)(baseb + off) = ub;
  }

  if (lane == 0) {
    sq[row] = s;
    const float* pp = pred + (size_t)row * NCLS;
    float v[NCLS];
    #pragma unroll
    for (int c = 0; c < NCLS; ++c) v[c] = pp[c];
    float m1 = v[0]; int i1 = 0;
    #pragma unroll
    for (int c = 1; c < NCLS; ++c)
      if (v[c] > m1) { m1 = v[c]; i1 = c; }
    float m2 = -INFINITY, sum = 0.f;
    #pragma unroll
    for (int c = 0; c < NCLS; ++c) {
      sum += __expf(v[c] - m1);
      if (c != i1) m2 = fmaxf(m2, v[c]);
    }
    const float d01 = (1.f - __expf(m2 - m1)) / sum;
    conf[row] = (d01 <= GAPV) || (i1 != cls);
  }
}

// ---- kernel 2: PURE Gram + hard mining — R11 structure at 4 blocks/CU ----
// Single change vs R11: __launch_bounds__(256,4) (VGPR cap 128; reg tally ~120).
// 16 waves/CU double the latency-hiding for barrier drains and ds_read->MFMA chains.
__global__ __launch_bounds__(256, 4) void gram_k(const char* __restrict__ xa,
                                                 const char* __restrict__ xbm,
                                                 const float* __restrict__ sq,
                                                 float* __restrict__ smax,
                                                 float* __restrict__ smin) {
  __shared__ char  ldsb[2][KSEG * 1024];   // per buf: 12 ksegs x 64 cols x 16B = 12 KB
  __shared__ float sqb[2][SLAB];
  const int tid  = threadIdx.x;
  const int wave = tid >> 6;
  const int lane = tid & 63;
  const int quad = lane >> 4;   // 0..3
  const int m16  = lane & 15;   // 0..15
  const int bx = blockIdx.x, by = blockIdx.y;

  // A fragments: rows bx*256 + wave*64 + rt*16 + m16, kseg = ks*4 + quad
  i32x4 A[4][NKS];
  #pragma unroll
  for (int rt = 0; rt < 4; ++rt) {
    const int rbase = wave * 64 + rt * 16;               // 0..240 within block rows
    const char* pa = xa + (size_t)(bx * 2 + (rbase >> 7)) * PTB
                        + (size_t)((rbase & 127) + m16) * 16;
    #pragma unroll
    for (int ks = 0; ks < NKS; ++ks)
      A[rt][ks] = *(const i32x4*)(pa + (size_t)(ks * 4 + quad) * 2048);
  }
  #pragma unroll
  for (int rt = 0; rt < 4; ++rt)
    #pragma unroll
    for (int ks = 0; ks < NKS; ++ks)
      asm("" : "+v"(A[rt][ks]));   // keep A resident

  float gmin[4][4], gmax[4][4];
  #pragma unroll
  for (int r = 0; r < 4; ++r)
    #pragma unroll
    for (int q = 0; q < 4; ++q) { gmin[r][q] = INFINITY; gmax[r][q] = -INFINITY; }

  // DMA slab 0: wave w stages ksegs 3w..3w+2; wave 3 lanes<16 also stage sq (64 floats)
  {
    const char* srcb = xbm + (size_t)(by * 4) * PTB;
    #pragma unroll
    for (int u = 0; u < 3; ++u) {
      const int kseg = wave * 3 + u;
      GLOAD_LDS16(srcb + (size_t)kseg * 2048 + lane * 16, &ldsb[0][kseg * 1024 + lane * 16]);
    }
    if (wave == 3 && lane < 16)
      GLOAD_LDS16((const char*)(sq + by * CHUNK) + lane * 16, (char*)&sqb[0][0] + lane * 16);
  }

  for (int s = 0; s < NSLAB; ++s) {
    __syncthreads();   // drains this wave's DMA + syncs buf ready
    if (s + 1 < NSLAB) {
      const char* srcb = xbm + (size_t)(by * 4 + ((s + 1) >> 1)) * PTB + ((s + 1) & 1) * 1024;
      char* dstb = &ldsb[(s + 1) & 1][0];
      #pragma unroll
      for (int u = 0; u < 3; ++u) {
        const int kseg = wave * 3 + u;
        GLOAD_LDS16(srcb + (size_t)kseg * 2048 + lane * 16, dstb + kseg * 1024 + lane * 16);
      }
      if (wave == 3 && lane < 16)
        GLOAD_LDS16((const char*)(sq + by * CHUNK + (s + 1) * SLAB) + lane * 16,
                    (char*)&sqb[(s + 1) & 1][0] + lane * 16);
    }
    // compute slab s: 4 j-tiles of 16 cols
    const char* buf = &ldsb[s & 1][0];
    #pragma unroll
    for (int jt = 0; jt < 4; ++jt) {
      i32x4 B[NKS];
      #pragma unroll
      for (int ks = 0; ks < NKS; ++ks)
        B[ks] = *(const i32x4*)(buf + (ks * 4 + quad) * 1024 + (jt * 16 + m16) * 16);
      const float sqj = sqb[s & 1][jt * 16 + m16];

      i32x4 acc[4];
      #pragma unroll
      for (int r = 0; r < 4; ++r) acc[r] = (i32x4){0, 0, 0, 0};
      #pragma unroll
      for (int ks = 0; ks < NKS; ++ks)
        #pragma unroll
        for (int r = 0; r < 4; ++r)
          acc[r] = __builtin_amdgcn_mfma_i32_16x16x64_i8(A[r][ks], B[ks], acc[r], 0, 0, 0);

      #pragma unroll
      for (int r = 0; r < 4; ++r)
        #pragma unroll
        for (int q = 0; q < 4; ++q) {
          const float cand = fmaf((float)acc[r][q], SCL, sqj);  // sq_j - 2dot + 504.03*same
          gmin[r][q] = fminf(gmin[r][q], cand);
          gmax[r][q] = fmaxf(gmax[r][q], cand);
        }
    }
  }

  // reduce over the 16 cols held across m16 lanes (quad bits preserved)
  #pragma unroll
  for (int m = 1; m <= 8; m <<= 1)
    #pragma unroll
    for (int r = 0; r < 4; ++r)
      #pragma unroll
      for (int q = 0; q < 4; ++q) {
        gmin[r][q] = fminf(gmin[r][q], __shfl_xor(gmin[r][q], m, 64));
        gmax[r][q] = fmaxf(gmax[r][q], __shfl_xor(gmax[r][q], m, 64));
      }

  if (m16 == 0) {  // lanes 0/16/32/48: quad q-block of 4 consecutive rows per r-tile
    const size_t sidx = (size_t)(bx * NCHUNK + by) * RGR;
    #pragma unroll
    for (int r = 0; r < 4; ++r) {
      const int lrow = wave * 64 + r * 16 + quad * 4;   // 0..252, multiple of 4
      *(float4*)&smax[sidx + lrow] = make_float4(gmax[r][0], gmax[r][1], gmax[r][2], gmax[r][3]);
      *(float4*)&smin[sidx + lrow] = make_float4(gmin[r][0], gmin[r][1], gmin[r][2], gmin[r][3]);
    }
  }
}

// ---- kernel 3: cross-chunk reduce + loss (32 blocks x 256 threads, 1 row/thread) ----
__global__ __launch_bounds__(256) void reduce_k(const float* __restrict__ smax,
                                                const float* __restrict__ smin,
                                                const float* __restrict__ sq,
                                                const int* __restrict__ conf,
                                                unsigned* __restrict__ ctrs,
                                                float* __restrict__ out) {
  __shared__ float red[2][4];
  const int tid = threadIdx.x, bx = blockIdx.x;
  const int wave = tid >> 6, lane = tid & 63;
  const int row = bx * RGR + tid;

  unsigned* g_done = ctrs;
  float*    Ssum   = (float*)(ctrs + 1);
  float*    Csum   = (float*)(ctrs + 2);

  float hi = -INFINITY, lo = INFINITY;
  #pragma unroll
  for (int c = 0; c < NCHUNK; ++c) {
    hi = fmaxf(hi, smax[(size_t)(bx * NCHUNK + c) * RGR + tid]);
    lo = fminf(lo, smin[(size_t)(bx * NCHUNK + c) * RGR + tid]);
  }
  float ps = 0.f, pc = 0.f;
  if (conf[row]) {
    const float ap = sqrtf(fmaxf(sq[row] + hi - DEBIAS, 1e-12f));  // hardest positive
    const float an = sqrtf(fmaxf(sq[row] + lo, 1e-12f));           // hardest negative
    ps = fmaxf(ap - an, 0.f);
    pc = 1.f;
  }
  #pragma unroll
  for (int m = 1; m < 64; m <<= 1) {
    ps += __shfl_xor(ps, m, 64);
    pc += __shfl_xor(pc, m, 64);
  }
  if (lane == 0) { red[0][wave] = ps; red[1][wave] = pc; }
  __syncthreads();
  if (tid == 0) {
    atomicAdd(Ssum, red[0][0] + red[0][1] + red[0][2] + red[0][3]);
    atomicAdd(Csum, red[1][0] + red[1][1] + red[1][2] + red[1][3]);
    __threadfence();
    if (atomicAdd(g_done, 1u) == NRG - 1u) {
      const float St = atomicAdd(Ssum, 0.f);
      const float Ct = atomicAdd(Csum, 0.f);
      out[0] = (Ct > 0.f) ? (St / fmaxf(Ct, 1.f)) : 0.f;
    }
  }
}

extern "C" void kernel_launch(void* const* d_in, const int* in_sizes, int n_in,
                              void* d_out, int out_size, void* d_ws, size_t ws_size,
                              hipStream_t stream) {
  const float* x    = (const float*)d_in[0];
  const float* pred = (const float*)d_in[1];
  const int*   tgt  = (const int*)d_in[2];
  float* out = (float*)d_out;

  char* w = (char*)d_ws;
  const size_t arr_bytes = (size_t)NROWS * KB;   // 1.57 MiB each (i8 panel layout)
  const size_t stg_bytes = (size_t)NRG * NCHUNK * RGR * 4;  // 512 KiB each
  char*     xa   = w;
  char*     xbm  = w + arr_bytes;
  float*    sq   = (float*)(w + 2 * arr_bytes);
  int*      conf = (int*)(w + 2 * arr_bytes + (size_t)NROWS * 4);
  float*    smax = (float*)(w + 2 * arr_bytes + (size_t)NROWS * 8);
  float*    smin = (float*)(w + 2 * arr_bytes + (size_t)NROWS * 8 + stg_bytes);
  unsigned* ctrs = (unsigned*)(w + 2 * arr_bytes + (size_t)NROWS * 8 + 2 * stg_bytes);

  hipLaunchKernelGGL(prep_k, dim3(NROWS / 4), dim3(256), 0, stream,
                     x, tgt, pred, xa, xbm, sq, conf, ctrs);
  hipLaunchKernelGGL(gram_k, dim3(NRG, NCHUNK), dim3(256), 0, stream,
                     xa, xbm, sq, smax, smin);
  hipLaunchKernelGGL(reduce_k, dim3(NRG), dim3(256), 0, stream,
                     smax, smin, sq, conf, ctrs, out);
}

// Round 14
// 84.351 us; speedup vs baseline: 1.4917x; 1.4917x over previous
//
#include <hip/hip_runtime.h>

#define NROWS 8192
#define DIMX  128              // raw feature dims
#define KB    192              // i8 K: 128 data + 40 one-hot (4/class) + 24 zero pad
#define KSEG  12               // 16B segments per row
#define PTB   24576            // bytes per 128-row panel tile (128*192)
#define NKS   3                // MFMA K-steps of 64
#define NCLS  10
#define GAPV  0.4f
#define DEBIAS 504.03125f      // 2*4*127*127/256 — exact fp32
#define SCL   (-0.0078125f)    // -2/256
#define RGR   256              // rows per block (4 waves x 64 rows)
#define NRG   (NROWS / RGR)        // 32 rowgroups
#define CHUNK 512              // cols per block
#define NCHUNK (NROWS / CHUNK)     // 16 col-chunks
#define SLAB  64               // cols per LDS slab
#define NSLAB (CHUNK / SLAB)       // 8 slabs

typedef __attribute__((ext_vector_type(4))) int i32x4;

// async 16B/lane global->LDS DMA
#define GLOAD_LDS16(g, l)                                              \
  __builtin_amdgcn_global_load_lds(                                    \
      (const __attribute__((address_space(1))) void*)(g),              \
      (__attribute__((address_space(3))) void*)(l), 16, 0, 0)

__device__ __forceinline__ int q8(float v) {  // round-to-nearest int8 of 16*x
  int q = (int)rintf(16.f * v);
  return q > 127 ? 127 : (q < -127 ? -127 : q);
}

// ---- kernel 1: build i8 PANEL arrays (K=192), sq, confusion, zero ctrs ----
// panel byte addr = (row>>7)*PTB + kseg*2048 + (row&127)*16 + (byte&15)
// row content: [q8(16x)[0..127], A:+127/B:-127 on dims 128+4c..131+4c for c=cls, 0 pad]
// => D = q_a . q_b = 256*dot_approx - 64516*[same]
//    cand = sq_j + SCL*D = sq_j - 2dot + 504.03125*[same]
__global__ __launch_bounds__(256) void prep_k(const float* __restrict__ x,
                                              const int* __restrict__ tgt,
                                              const float* __restrict__ pred,
                                              char* __restrict__ xa,
                                              char* __restrict__ xbm,
                                              float* __restrict__ sq,
                                              int* __restrict__ conf,
                                              unsigned* __restrict__ ctrs) {
  if (blockIdx.x == 0 && threadIdx.x < 3) ctrs[threadIdx.x] = 0u;  // g_done, Ssum, Csum

  const int wave = threadIdx.x >> 6;
  const int lane = threadIdx.x & 63;
  const int row  = blockIdx.x * 4 + wave;
  const float2 f2 = ((const float2*)(x + (size_t)row * DIMX))[lane];
  float s = f2.x * f2.x + f2.y * f2.y;
  #pragma unroll
  for (int m = 1; m < 64; m <<= 1) s += __shfl_xor(s, m, 64);

  char* basea = xa  + (size_t)(row >> 7) * PTB + (size_t)(row & 127) * 16;
  char* baseb = xbm + (size_t)(row >> 7) * PTB + (size_t)(row & 127) * 16;
  {  // data elems e=2L,2L+1 -> kseg = L>>3, byte (L&7)*2
    const int q0 = q8(f2.x), q1 = q8(f2.y);
    const unsigned short u = (unsigned short)((q0 & 0xFF) | ((q1 & 0xFF) << 8));
    const size_t off = (size_t)(lane >> 3) * 2048 + (lane & 7) * 2;
    *(unsigned short*)(basea + off) = u;
    *(unsigned short*)(baseb + off) = u;
  }
  const int cls = tgt[row];
  if (lane < 32) {  // aug elems e = 128 + j, j = 2*lane, 2*lane+1
    const int j = 2 * lane;
    const int c = j >> 2;                  // class block (4 dims each)
    const bool hit = (c < NCLS) && (c == cls);
    const unsigned short ua = hit ? (unsigned short)0x7F7F : 0;  // +127,+127
    const unsigned short ub = hit ? (unsigned short)0x8181 : 0;  // -127,-127
    const size_t off = (size_t)(8 + (j >> 4)) * 2048 + (j & 15);
    *(unsigned short*)(basea + off) = ua;
    *(unsigned short*)(baseb + off) = ub;
  }

  if (lane == 0) {
    sq[row] = s;
    const float* pp = pred + (size_t)row * NCLS;
    float v[NCLS];
    #pragma unroll
    for (int c = 0; c < NCLS; ++c) v[c] = pp[c];
    float m1 = v[0]; int i1 = 0;
    #pragma unroll
    for (int c = 1; c < NCLS; ++c)
      if (v[c] > m1) { m1 = v[c]; i1 = c; }
    float m2 = -INFINITY, sum = 0.f;
    #pragma unroll
    for (int c = 0; c < NCLS; ++c) {
      sum += __expf(v[c] - m1);
      if (c != i1) m2 = fmaxf(m2, v[c]);
    }
    const float d01 = (1.f - __expf(m2 - m1)) / sum;
    conf[row] = (d01 <= GAPV) || (i1 != cls);
  }
}

// ---- kernel 2: PURE Gram + hard mining — R11 structure, waves_per_eu(3,4) ----
// Single change vs R11: amdgpu_waves_per_eu(3,4). min=3 -> VGPR cap ~170 (tally
// ~125 fits, NO spill possible); max=4 -> forbids the R13 64-VGPR/8-wave shrink
// that spilled A to scratch (WRITE_SIZE 46 MB). Target: 12-16 waves/CU.
__global__ __launch_bounds__(256)
__attribute__((amdgpu_waves_per_eu(3, 4)))
void gram_k(const char* __restrict__ xa,
            const char* __restrict__ xbm,
            const float* __restrict__ sq,
            float* __restrict__ smax,
            float* __restrict__ smin) {
  __shared__ char  ldsb[2][KSEG * 1024];   // per buf: 12 ksegs x 64 cols x 16B = 12 KB
  __shared__ float sqb[2][SLAB];
  const int tid  = threadIdx.x;
  const int wave = tid >> 6;
  const int lane = tid & 63;
  const int quad = lane >> 4;   // 0..3
  const int m16  = lane & 15;   // 0..15
  const int bx = blockIdx.x, by = blockIdx.y;

  // A fragments: rows bx*256 + wave*64 + rt*16 + m16, kseg = ks*4 + quad
  i32x4 A[4][NKS];
  #pragma unroll
  for (int rt = 0; rt < 4; ++rt) {
    const int rbase = wave * 64 + rt * 16;               // 0..240 within block rows
    const char* pa = xa + (size_t)(bx * 2 + (rbase >> 7)) * PTB
                        + (size_t)((rbase & 127) + m16) * 16;
    #pragma unroll
    for (int ks = 0; ks < NKS; ++ks)
      A[rt][ks] = *(const i32x4*)(pa + (size_t)(ks * 4 + quad) * 2048);
  }
  #pragma unroll
  for (int rt = 0; rt < 4; ++rt)
    #pragma unroll
    for (int ks = 0; ks < NKS; ++ks)
      asm("" : "+v"(A[rt][ks]));   // keep A resident

  float gmin[4][4], gmax[4][4];
  #pragma unroll
  for (int r = 0; r < 4; ++r)
    #pragma unroll
    for (int q = 0; q < 4; ++q) { gmin[r][q] = INFINITY; gmax[r][q] = -INFINITY; }

  // DMA slab 0: wave w stages ksegs 3w..3w+2; wave 3 lanes<16 also stage sq (64 floats)
  {
    const char* srcb = xbm + (size_t)(by * 4) * PTB;
    #pragma unroll
    for (int u = 0; u < 3; ++u) {
      const int kseg = wave * 3 + u;
      GLOAD_LDS16(srcb + (size_t)kseg * 2048 + lane * 16, &ldsb[0][kseg * 1024 + lane * 16]);
    }
    if (wave == 3 && lane < 16)
      GLOAD_LDS16((const char*)(sq + by * CHUNK) + lane * 16, (char*)&sqb[0][0] + lane * 16);
  }

  for (int s = 0; s < NSLAB; ++s) {
    __syncthreads();   // drains this wave's DMA + syncs buf ready
    if (s + 1 < NSLAB) {
      const char* srcb = xbm + (size_t)(by * 4 + ((s + 1) >> 1)) * PTB + ((s + 1) & 1) * 1024;
      char* dstb = &ldsb[(s + 1) & 1][0];
      #pragma unroll
      for (int u = 0; u < 3; ++u) {
        const int kseg = wave * 3 + u;
        GLOAD_LDS16(srcb + (size_t)kseg * 2048 + lane * 16, dstb + kseg * 1024 + lane * 16);
      }
      if (wave == 3 && lane < 16)
        GLOAD_LDS16((const char*)(sq + by * CHUNK + (s + 1) * SLAB) + lane * 16,
                    (char*)&sqb[(s + 1) & 1][0] + lane * 16);
    }
    // compute slab s: 4 j-tiles of 16 cols
    const char* buf = &ldsb[s & 1][0];
    #pragma unroll
    for (int jt = 0; jt < 4; ++jt) {
      i32x4 B[NKS];
      #pragma unroll
      for (int ks = 0; ks < NKS; ++ks)
        B[ks] = *(const i32x4*)(buf + (ks * 4 + quad) * 1024 + (jt * 16 + m16) * 16);
      const float sqj = sqb[s & 1][jt * 16 + m16];

      i32x4 acc[4];
      #pragma unroll
      for (int r = 0; r < 4; ++r) acc[r] = (i32x4){0, 0, 0, 0};
      #pragma unroll
      for (int ks = 0; ks < NKS; ++ks)
        #pragma unroll
        for (int r = 0; r < 4; ++r)
          acc[r] = __builtin_amdgcn_mfma_i32_16x16x64_i8(A[r][ks], B[ks], acc[r], 0, 0, 0);

      #pragma unroll
      for (int r = 0; r < 4; ++r)
        #pragma unroll
        for (int q = 0; q < 4; ++q) {
          const float cand = fmaf((float)acc[r][q], SCL, sqj);  // sq_j - 2dot + 504.03*same
          gmin[r][q] = fminf(gmin[r][q], cand);
          gmax[r][q] = fmaxf(gmax[r][q], cand);
        }
    }
  }

  // reduce over the 16 cols held across m16 lanes (quad bits preserved)
  #pragma unroll
  for (int m = 1; m <= 8; m <<= 1)
    #pragma unroll
    for (int r = 0; r < 4; ++r)
      #pragma unroll
      for (int q = 0; q < 4; ++q) {
        gmin[r][q] = fminf(gmin[r][q], __shfl_xor(gmin[r][q], m, 64));
        gmax[r][q] = fmaxf(gmax[r][q], __shfl_xor(gmax[r][q], m, 64));
      }

  if (m16 == 0) {  // lanes 0/16/32/48: quad q-block of 4 consecutive rows per r-tile
    const size_t sidx = (size_t)(bx * NCHUNK + by) * RGR;
    #pragma unroll
    for (int r = 0; r < 4; ++r) {
      const int lrow = wave * 64 + r * 16 + quad * 4;   // 0..252, multiple of 4
      *(float4*)&smax[sidx + lrow] = make_float4(gmax[r][0], gmax[r][1], gmax[r][2], gmax[r][3]);
      *(float4*)&smin[sidx + lrow] = make_float4(gmin[r][0], gmin[r][1], gmin[r][2], gmin[r][3]);
    }
  }
}

// ---- kernel 3: cross-chunk reduce + loss (32 blocks x 256 threads, 1 row/thread) ----
__global__ __launch_bounds__(256) void reduce_k(const float* __restrict__ smax,
                                                const float* __restrict__ smin,
                                                const float* __restrict__ sq,
                                                const int* __restrict__ conf,
                                                unsigned* __restrict__ ctrs,
                                                float* __restrict__ out) {
  __shared__ float red[2][4];
  const int tid = threadIdx.x, bx = blockIdx.x;
  const int wave = tid >> 6, lane = tid & 63;
  const int row = bx * RGR + tid;

  unsigned* g_done = ctrs;
  float*    Ssum   = (float*)(ctrs + 1);
  float*    Csum   = (float*)(ctrs + 2);

  float hi = -INFINITY, lo = INFINITY;
  #pragma unroll
  for (int c = 0; c < NCHUNK; ++c) {
    hi = fmaxf(hi, smax[(size_t)(bx * NCHUNK + c) * RGR + tid]);
    lo = fminf(lo, smin[(size_t)(bx * NCHUNK + c) * RGR + tid]);
  }
  float ps = 0.f, pc = 0.f;
  if (conf[row]) {
    const float ap = sqrtf(fmaxf(sq[row] + hi - DEBIAS, 1e-12f));  // hardest positive
    const float an = sqrtf(fmaxf(sq[row] + lo, 1e-12f));           // hardest negative
    ps = fmaxf(ap - an, 0.f);
    pc = 1.f;
  }
  #pragma unroll
  for (int m = 1; m < 64; m <<= 1) {
    ps += __shfl_xor(ps, m, 64);
    pc += __shfl_xor(pc, m, 64);
  }
  if (lane == 0) { red[0][wave] = ps; red[1][wave] = pc; }
  __syncthreads();
  if (tid == 0) {
    atomicAdd(Ssum, red[0][0] + red[0][1] + red[0][2] + red[0][3]);
    atomicAdd(Csum, red[1][0] + red[1][1] + red[1][2] + red[1][3]);
    __threadfence();
    if (atomicAdd(g_done, 1u) == NRG - 1u) {
      const float St = atomicAdd(Ssum, 0.f);
      const float Ct = atomicAdd(Csum, 0.f);
      out[0] = (Ct > 0.f) ? (St / fmaxf(Ct, 1.f)) : 0.f;
    }
  }
}

extern "C" void kernel_launch(void* const* d_in, const int* in_sizes, int n_in,
                              void* d_out, int out_size, void* d_ws, size_t ws_size,
                              hipStream_t stream) {
  const float* x    = (const float*)d_in[0];
  const float* pred = (const float*)d_in[1];
  const int*   tgt  = (const int*)d_in[2];
  float* out = (float*)d_out;

  char* w = (char*)d_ws;
  const size_t arr_bytes = (size_t)NROWS * KB;   // 1.57 MiB each (i8 panel layout)
  const size_t stg_bytes = (size_t)NRG * NCHUNK * RGR * 4;  // 512 KiB each
  char*     xa   = w;
  char*     xbm  = w + arr_bytes;
  float*    sq   = (float*)(w + 2 * arr_bytes);
  int*      conf = (int*)(w + 2 * arr_bytes + (size_t)NROWS * 4);
  float*    smax = (float*)(w + 2 * arr_bytes + (size_t)NROWS * 8);
  float*    smin = (float*)(w + 2 * arr_bytes + (size_t)NROWS * 8 + stg_bytes);
  unsigned* ctrs = (unsigned*)(w + 2 * arr_bytes + (size_t)NROWS * 8 + 2 * stg_bytes);

  hipLaunchKernelGGL(prep_k, dim3(NROWS / 4), dim3(256), 0, stream,
                     x, tgt, pred, xa, xbm, sq, conf, ctrs);
  hipLaunchKernelGGL(gram_k, dim3(NRG, NCHUNK), dim3(256), 0, stream,
                     xa, xbm, sq, smax, smin);
  hipLaunchKernelGGL(reduce_k, dim3(NRG), dim3(256), 0, stream,
                     smax, smin, sq, conf, ctrs, out);
}